// Round 4
// baseline (229.284 us; speedup 1.0000x reference)
//
#include <hip/hip_runtime.h>

// ConvSoftArgmax2d: x (8,16,512,512) fp32 -> coords (128,2,256,256), resp (128,1,256,256)
// 3x3 window, stride 2, pad 1. Padding contributes 0 to the pooled exp-sums.
// v3.1: 2x2 outputs/thread — 5 float4 row loads for 4 outputs, shared middle row
//       reused in registers (read amplification 1.5x -> 1.25x). Plain stores.
//       XCD-chunked swizzle. Left column via shfl of e3 / e3*v.w.
//       FIX vs v3: boundary-lane reload used (rowp)[cM-1] but rowp already
//       includes cM — correct index is (rowp)[-1].

#define H  512
#define W  512
#define HO 256
#define WO 256
#define BC 128

__global__ __launch_bounds__(256) void casm_kernel(
    const float* __restrict__ x, const float* __restrict__ temp,
    float* __restrict__ out)
{
    // XCD-chunked swizzle: nblk = 8192 (divisible by 8). Keeps ho-adjacent
    // blocks (which share boundary input rows) on the same XCD's L2.
    int nblk = gridDim.x;
    int bid  = blockIdx.x;
    int swz  = (bid & 7) * (nblk >> 3) + (bid >> 3);

    int idx = swz * 256 + (int)threadIdx.x;
    int t   = idx & 127;               // col-pair: wo = 2t, 2t+1
    int hp  = (idx >> 7) & 127;        // ho-pair:  ho = 2hp, 2hp+1 (wave-uniform)
    int bc  = idx >> 14;

    // exp(v/T) = exp2(v * log2e / T)
    float k = 1.44269504088896340736f / fmaxf(temp[0], 1e-8f);

    const float* __restrict__ xp = x + (size_t)bc * (H * W);
    int  cM   = 4 * t;                 // 16B-aligned float4 column base
    float mL  = (t == 0) ? 0.0f : 1.0f;          // wo==0 left-pad mask
    bool bfix = ((t & 63) == 0) && (t != 0);     // wave-boundary lane (t==64)
    bool r0ok = (hp != 0);                       // top row exists (wave-uniform)

    // rows 4hp-1 .. 4hp+3 ; ho0 uses rows {0,1,2}, ho1 uses rows {2,3,4}
    const float* __restrict__ rb = xp + (size_t)(4 * hp) * W + cM;   // row 4hp, col 4t
    float4 v0 = make_float4(0.f, 0.f, 0.f, 0.f);
    if (r0ok) v0 = *(const float4*)(rb - W);
    float4 v1 = *(const float4*)(rb);
    float4 v2 = *(const float4*)(rb + W);
    float4 v3 = *(const float4*)(rb + 2 * W);
    float4 v4 = *(const float4*)(rb + 3 * W);

#define EXPK(u) __builtin_amdgcn_exp2f(k * (u))
    // per-row: rsA/rsB window row-sums, dxA/dxB right-left col diff, nA/nB value-weighted
    // rowp points at col cM of the row, so the left-neighbor col 4t-1 is rowp[-1].
#define ROW(v, rowp, rsA, rsB, dxA, dxB, nA, nB) {                       \
        float e0 = EXPK((v).x), e1 = EXPK((v).y);                        \
        float e2 = EXPK((v).z), e3 = EXPK((v).w);                        \
        float p3 = e3 * (v).w;                                           \
        float eL = __shfl_up(e3, 1);                                     \
        float pL = __shfl_up(p3, 1);                                     \
        if (bfix) { float vl = (rowp)[-1]; eL = EXPK(vl); pL = eL * vl; } \
        eL *= mL; pL *= mL;                                              \
        rsA = eL + e0 + e1;  rsB = e1 + e2 + e3;                         \
        dxA = e1 - eL;       dxB = e3 - e1;                              \
        nA  = pL + fmaf(e0, (v).x, e1 * (v).y);                          \
        nB  = fmaf(e1, (v).y, fmaf(e2, (v).z, p3)); }

    float rsA, rsB, dxA, dxB, nA, nB;

    // ho0 accumulators (window A = wo 2t, window B = wo 2t+1), then ho1
    float d0A = 0, d0B = 0, cy0A = 0, cy0B = 0, x0A = 0, x0B = 0, m0A = 0, m0B = 0;
    float d1A = 0, d1B = 0, cy1A = 0, cy1B = 0, x1A = 0, x1B = 0, m1A = 0, m1B = 0;

    if (r0ok) {                       // row 4hp-1: ho0 top
        ROW(v0, rb - W, rsA, rsB, dxA, dxB, nA, nB);
        d0A += rsA; d0B += rsB; cy0A -= rsA; cy0B -= rsB;
        x0A += dxA; x0B += dxB; m0A += nA;  m0B += nB;
    }
    {                                  // row 4hp: ho0 mid
        ROW(v1, rb, rsA, rsB, dxA, dxB, nA, nB);
        d0A += rsA; d0B += rsB; x0A += dxA; x0B += dxB; m0A += nA; m0B += nB;
    }
    {                                  // row 4hp+1: ho0 bottom + ho1 top (shared)
        ROW(v2, rb + W, rsA, rsB, dxA, dxB, nA, nB);
        d0A += rsA; d0B += rsB; cy0A += rsA; cy0B += rsB;
        x0A += dxA; x0B += dxB; m0A += nA;  m0B += nB;
        d1A += rsA; d1B += rsB; cy1A -= rsA; cy1B -= rsB;
        x1A += dxA; x1B += dxB; m1A += nA;  m1B += nB;
    }
    {                                  // row 4hp+2: ho1 mid
        ROW(v3, rb + 2 * W, rsA, rsB, dxA, dxB, nA, nB);
        d1A += rsA; d1B += rsB; x1A += dxA; x1B += dxB; m1A += nA; m1B += nB;
    }
    {                                  // row 4hp+3: ho1 bottom
        ROW(v4, rb + 3 * W, rsA, rsB, dxA, dxB, nA, nB);
        d1A += rsA; d1B += rsB; cy1A += rsA; cy1B += rsB;
        x1A += dxA; x1B += dxB; m1A += nA;  m1B += nB;
    }
#undef ROW
#undef EXPK

    const float scale = 2.0f / 511.0f;
    int wo0 = 2 * t;
    int ho0 = 2 * hp;

    float i0A = __builtin_amdgcn_rcpf(d0A + 1e-12f);
    float i0B = __builtin_amdgcn_rcpf(d0B + 1e-12f);
    float i1A = __builtin_amdgcn_rcpf(d1A + 1e-12f);
    float i1B = __builtin_amdgcn_rcpf(d1B + 1e-12f);

    size_t pix0  = (size_t)ho0 * WO + wo0;           // even wo -> 8B aligned
    size_t cbase = (size_t)bc * (2 * HO * WO);
    size_t rbase = (size_t)BC * 2 * HO * WO + (size_t)bc * HO * WO;

    // ho0 outputs
    *(float2*)(out + cbase + pix0) =
        make_float2((x0A * i0A + (float)(2 * wo0)) * scale - 1.0f,
                    (x0B * i0B + (float)(2 * wo0 + 2)) * scale - 1.0f);
    *(float2*)(out + cbase + HO * WO + pix0) =
        make_float2((cy0A * i0A + (float)(2 * ho0)) * scale - 1.0f,
                    (cy0B * i0B + (float)(2 * ho0)) * scale - 1.0f);
    *(float2*)(out + rbase + pix0) = make_float2(m0A * i0A, m0B * i0B);

    // ho1 outputs
    size_t pix1 = pix0 + WO;
    *(float2*)(out + cbase + pix1) =
        make_float2((x1A * i1A + (float)(2 * wo0)) * scale - 1.0f,
                    (x1B * i1B + (float)(2 * wo0 + 2)) * scale - 1.0f);
    *(float2*)(out + cbase + HO * WO + pix1) =
        make_float2((cy1A * i1A + (float)(2 * ho0 + 2)) * scale - 1.0f,
                    (cy1B * i1B + (float)(2 * ho0 + 2)) * scale - 1.0f);
    *(float2*)(out + rbase + pix1) = make_float2(m1A * i1A, m1B * i1B);
}

extern "C" void kernel_launch(void* const* d_in, const int* in_sizes, int n_in,
                              void* d_out, int out_size, void* d_ws, size_t ws_size,
                              hipStream_t stream) {
    const float* x    = (const float*)d_in[0];
    const float* temp = (const float*)d_in[1];
    float* out        = (float*)d_out;

    int total  = BC * (HO / 2) * (WO / 2);  // 2,097,152 threads, 4 outputs each
    int blocks = total / 256;               // 8192
    casm_kernel<<<blocks, 256, 0, stream>>>(x, temp, out);
}

// Round 5
// 214.796 us; speedup vs baseline: 1.0674x; 1.0674x over previous
//
#include <hip/hip_runtime.h>

// ConvSoftArgmax2d: x (8,16,512,512) fp32 -> coords (128,2,256,256), resp (128,1,256,256)
// 3x3 window, stride 2, pad 1. Padding contributes 0 to the pooled exp-sums.
// v4: revert to the v1 structure (best measured: 218 µs total) with ONE change:
//     each row's 3 columns (2wo-1, 2wo, 2wo+1) come from a single dword-aligned
//     float4 at col 2wo-2 (discard .x), instead of scalar + float2 (6 loads -> 3).
//     wo==0 lane clamps base to 0 and selects .x/.y via predicated moves.
//     No swizzle, no shfl, no ds ops, scalar stores as in v1.

#define H  512
#define W  512
#define HO 256
#define WO 256
#define BC 128

__global__ __launch_bounds__(256) void casm_kernel(
    const float* __restrict__ x, const float* __restrict__ temp,
    float* __restrict__ out)
{
    int idx = blockIdx.x * 256 + threadIdx.x;
    int wo = idx & (WO - 1);
    int ho = (idx >> 8) & (HO - 1);   // block-uniform (256 threads = one wo-row)
    int bc = idx >> 16;

    // exp(v/T) = exp2(v * log2e / T)
    float k = 1.44269504088896340736f / fmaxf(temp[0], 1e-8f);

    const float* __restrict__ xp = x + (size_t)bc * (H * W);
    int r0 = 2 * ho - 1;              // only ho==0 gives r0 < 0 (block-uniform)

    bool  w0 = (wo == 0);
    int   cb = w0 ? 0 : (2 * wo - 2); // float4 base col (dword/8B aligned)
    float mL = w0 ? 0.0f : 1.0f;      // left-column pad mask

#define EXPK(u) __builtin_amdgcn_exp2f(k * (u))
    // One float4 per row: cols cb..cb+3. Normal lanes: (L,M,R) = (.y,.z,.w).
    // wo==0 lane: base clamped to 0 -> (M,R) = (.x,.y), L masked to zero.
#define ROWX(rowptr, rs) {                                   \
        float4 v = *(const float4*)((rowptr) + cb);          \
        float vL = v.y;                                      \
        float vM = w0 ? v.x : v.z;                           \
        float vR = w0 ? v.y : v.w;                           \
        float eL = mL * EXPK(vL);                            \
        float eM = EXPK(vM);                                 \
        float eR = EXPK(vR);                                 \
        rs = eL + eM + eR;                                   \
        colL += eL;  colR += eR;                             \
        numv = fmaf(eL, vL, fmaf(eM, vM, fmaf(eR, vR, numv))); }

    float s0 = 0.f, s1, s2;           // per-row exp sums
    float colL = 0.f, colR = 0.f, numv = 0.f;

    if (r0 >= 0) ROWX(xp + r0 * W, s0);        // row 0 (block-uniform skip)
    ROWX(xp + (r0 + 1) * W, s1);               // row 1 (always in bounds)
    ROWX(xp + (r0 + 2) * W, s2);               // row 2 (always in bounds)
#undef ROWX
#undef EXPK

    float den = s0 + s1 + s2 + 1e-12f;
    float inv_den = __builtin_amdgcn_rcpf(den);
    const float scale = 2.0f / 511.0f;
    float cx   = ((colR - colL) * inv_den + (float)(2 * wo)) * scale - 1.0f;
    float cy   = ((s2 - s0)    * inv_den + (float)(2 * ho)) * scale - 1.0f;
    float resp = numv * inv_den;

    size_t pix   = (size_t)ho * WO + wo;
    size_t cbase = (size_t)bc * (2 * HO * WO) + pix;
    out[cbase]           = cx;                                     // channel 0: x
    out[cbase + HO * WO] = cy;                                     // channel 1: y
    out[(size_t)BC * 2 * HO * WO + (size_t)bc * HO * WO + pix] = resp;
}

extern "C" void kernel_launch(void* const* d_in, const int* in_sizes, int n_in,
                              void* d_out, int out_size, void* d_ws, size_t ws_size,
                              hipStream_t stream) {
    const float* x    = (const float*)d_in[0];
    const float* temp = (const float*)d_in[1];
    float* out        = (float*)d_out;

    int total  = BC * HO * WO;          // 8,388,608 output pixels
    int blocks = total / 256;           // 32768
    casm_kernel<<<blocks, 256, 0, stream>>>(x, temp, out);
}